// Round 3
// baseline (365.338 us; speedup 1.0000x reference)
//
#include <hip/hip_runtime.h>

// AttentionLoRA: B=1, S=4096, D=1024, H=16, HD=64.
// Pipeline: cvt_all(f32->bf16 + bias pack) -> QKV NT-GEMM (bf16 MFMA, scatter epilogue)
//           -> RoPE (q pre-scaled by 0.125*log2e) -> V transpose -> flash attention
//           (128-row q blocks, 32 q-rows/wave, K in LDS, V direct-from-global,
//            exp2 softmax, no running max) -> out-proj GEMM (f32 out).

#define S_LEN 4096
#define DIM   1024
#define NH    16
#define HD    64

typedef __attribute__((ext_vector_type(8))) short bf16x8;   // 8 bf16 = 4 VGPRs
typedef __attribute__((ext_vector_type(4))) float f32x4;

__device__ __forceinline__ unsigned short f2b(float f) {
  union { float f; unsigned int u; } v; v.f = f;
  unsigned int r = (v.u + 0x7fffu + ((v.u >> 16) & 1u)) >> 16;  // RNE
  return (unsigned short)r;
}
__device__ __forceinline__ float b2f(unsigned short h) {
  union { unsigned int u; float f; } v; v.u = ((unsigned int)h) << 16;
  return v.f;
}
// pack two f32 -> two bf16 by truncation (p in [0,1]; <=1ulp)
__device__ __forceinline__ unsigned int pk2t(float a, float b) {
  union { float f; unsigned int u; } x, y; x.f = a; y.f = b;
  return (x.u >> 16) | (y.u & 0xffff0000u);
}
__device__ __forceinline__ void gload16(const void* g, void* l) {
  __builtin_amdgcn_global_load_lds(
      (const __attribute__((address_space(1))) unsigned int*)g,
      (__attribute__((address_space(3))) unsigned int*)l, 16, 0, 0);
}
__device__ __forceinline__ f32x4 fzero4() { f32x4 z = {0.f, 0.f, 0.f, 0.f}; return z; }

// ---------------- fused f32->bf16 convert (x, wq, wk, wv, wo) + bias pack ----------
__global__ void cvt_all(const float* __restrict__ x, const float* __restrict__ wq,
                        const float* __restrict__ wk, const float* __restrict__ wv,
                        const float* __restrict__ wo, const float* __restrict__ qb,
                        const float* __restrict__ kb, const float* __restrict__ vbs,
                        const float* __restrict__ ob, unsigned short* __restrict__ xb,
                        unsigned short* __restrict__ wqkvb, unsigned short* __restrict__ wobb,
                        float* __restrict__ biasq, float* __restrict__ biaso) {
  int i = blockIdx.x * 256 + threadIdx.x;  // float4 index
  if (i < 2097152) {
    const float* src; unsigned short* dst; int off;
    if (i < 1048576)      { src = x;  dst = xb;              off = i; }
    else if (i < 1310720) { src = wq; dst = wqkvb;           off = i - 1048576; }
    else if (i < 1572864) { src = wk; dst = wqkvb + 1048576; off = i - 1310720; }
    else if (i < 1835008) { src = wv; dst = wqkvb + 2097152; off = i - 1572864; }
    else                  { src = wo; dst = wobb;            off = i - 1835008; }
    float4 v = ((const float4*)src)[off];
    unsigned int lo = (unsigned int)f2b(v.x) | ((unsigned int)f2b(v.y) << 16);
    unsigned int hi = (unsigned int)f2b(v.z) | ((unsigned int)f2b(v.w) << 16);
    ((uint2*)dst)[off] = make_uint2(lo, hi);
  } else if (i < 2097152 + 1024) {
    int j = i - 2097152;
    if (j < 256)      ((float4*)biasq)[j]              = ((const float4*)qb)[j];
    else if (j < 512) ((float4*)(biasq + 1024))[j-256] = ((const float4*)kb)[j-256];
    else if (j < 768) ((float4*)(biasq + 2048))[j-512] = ((const float4*)vbs)[j-512];
    else              ((float4*)biaso)[j-768]          = ((const float4*)ob)[j-768];
  }
}

// ---------------- NT GEMM: C[m,n] = sum_k A[m,k]*B[n,k] + bias[n] ----------------
// m97 structure: 128x128 tile, BK=32, 4 waves each 64x64 (4x4 of 16x16x32 MFMA).
// mode 0: scatter to q/k/v bf16 (h,s,hd).  mode 1: f32 row-major out.
__global__ __launch_bounds__(256) void gemm_nt(
    const unsigned short* __restrict__ A, const unsigned short* __restrict__ B,
    const float* __restrict__ bias, float* __restrict__ outF,
    unsigned short* __restrict__ dq, unsigned short* __restrict__ dk,
    unsigned short* __restrict__ dv, int M, int N, int K, int mode) {
  __shared__ alignas(16) unsigned short sA[128 * 32];
  __shared__ alignas(16) unsigned short sB[128 * 32];
  const int tid = threadIdx.x;
  const int lane = tid & 63, wave = tid >> 6;
  const int ln = lane & 15, quad = lane >> 4;
  const int bm = blockIdx.x * 128, bn = blockIdx.y * 128;
  const int wr = (wave >> 1) * 64, wc = (wave & 1) * 64;

  f32x4 acc[4][4];
#pragma unroll
  for (int i = 0; i < 4; ++i)
#pragma unroll
    for (int j = 0; j < 4; ++j) acc[i][j] = fzero4();

  for (int k0 = 0; k0 < K; k0 += 32) {
    __syncthreads();
#pragma unroll
    for (int i = 0; i < 2; ++i) {
      int o = (i * 256 + tid) * 16;
      int e = o >> 1;
      int row = e >> 5, col = e & 31;
      gload16(A + (size_t)(bm + row) * K + k0 + col, (char*)sA + o);
      gload16(B + (size_t)(bn + row) * K + k0 + col, (char*)sB + o);
    }
    __syncthreads();
    bf16x8 af[4], bfr[4];
#pragma unroll
    for (int i = 0; i < 4; ++i) {
      af[i]  = *(const bf16x8*)&sA[(wr + i * 16 + ln) * 32 + quad * 8];
      bfr[i] = *(const bf16x8*)&sB[(wc + i * 16 + ln) * 32 + quad * 8];
    }
#pragma unroll
    for (int i = 0; i < 4; ++i)
#pragma unroll
      for (int j = 0; j < 4; ++j)
        acc[i][j] = __builtin_amdgcn_mfma_f32_16x16x32_bf16(af[i], bfr[j], acc[i][j], 0, 0, 0);
  }

  if (mode == 1) {
#pragma unroll
    for (int i = 0; i < 4; ++i)
#pragma unroll
      for (int j = 0; j < 4; ++j) {
        int n = bn + wc + j * 16 + ln;
        float bi = bias[n];
#pragma unroll
        for (int r = 0; r < 4; ++r) {
          int m = bm + wr + i * 16 + quad * 4 + r;
          outF[(size_t)m * N + n] = acc[i][j][r] + bi;
        }
      }
  } else {
    const int bufi = bn >> 10;
    unsigned short* const base = bufi == 0 ? dq : (bufi == 1 ? dk : dv);
    const int hq = ((bn & 1023) + wc) >> 6;  // head index, wave-uniform
#pragma unroll
    for (int i = 0; i < 4; ++i)
#pragma unroll
      for (int j = 0; j < 4; ++j) {
        int n = bn + wc + j * 16 + ln;
        float bi = bias[n];
        int hd = j * 16 + ln;
#pragma unroll
        for (int r = 0; r < 4; ++r) {
          int m = bm + wr + i * 16 + quad * 4 + r;
          base[((size_t)(hq * S_LEN + m)) * HD + hd] = f2b(acc[i][j][r] + bi);
        }
      }
  }
}

// ---------------- RoPE in-place on q,k (h,s,hd); q pre-scaled by 0.125*log2e ------
__global__ void rope_kernel(unsigned short* __restrict__ q, unsigned short* __restrict__ k,
                            const float* __restrict__ fc, const float* __restrict__ fs) {
  int idx = blockIdx.x * 256 + threadIdx.x;  // 2 * 16*4096*8
  const int P = NH * S_LEN * 8;
  bool isq = idx < P;
  unsigned short* t = isq ? q : k;
  int i = isq ? idx : idx - P;
  int g = i & 7;
  int s = (i >> 3) & 4095;
  int h = i >> 15;
  const float scale = isq ? 0.180336880f : 1.0f;  // (1/8)*log2(e) folded into q
  float4 c4 = *(const float4*)&fc[s * 32 + g * 4];
  float4 s4 = *(const float4*)&fs[s * 32 + g * 4];
  uint4* p = (uint4*)&t[((size_t)(h * S_LEN + s)) * HD + g * 8];
  uint4 pv = *p;
  auto rot = [&](unsigned int w, float c, float sn) -> unsigned int {
    float x0 = b2f((unsigned short)(w & 0xffffu));
    float x1 = b2f((unsigned short)(w >> 16));
    float o0 = (x0 * c - x1 * sn) * scale;
    float o1 = (x0 * sn + x1 * c) * scale;
    return (unsigned int)f2b(o0) | ((unsigned int)f2b(o1) << 16);
  };
  pv.x = rot(pv.x, c4.x, s4.x);
  pv.y = rot(pv.y, c4.y, s4.y);
  pv.z = rot(pv.z, c4.z, s4.z);
  pv.w = rot(pv.w, c4.w, s4.w);
  *p = pv;
}

// ---------------- V transpose: (h,s,hd) -> (h,hd,s) ----------------
__global__ void transpose_v(const unsigned short* __restrict__ v, unsigned short* __restrict__ vt) {
  __shared__ unsigned short t[64][65];
  const int h = blockIdx.y;
  const int s0 = blockIdx.x * 64;
  const int tid = threadIdx.x;
  const int r = tid >> 2, c0 = (tid & 3) * 16;
  const unsigned short* src = v + ((size_t)h * S_LEN + s0 + r) * HD + c0;
#pragma unroll
  for (int j = 0; j < 16; ++j) t[r][c0 + j] = src[j];
  __syncthreads();
  unsigned short* dst = vt + ((size_t)h * HD + r) * S_LEN + s0 + c0;
#pragma unroll
  for (int j = 0; j < 16; ++j) dst[j] = t[c0 + j][r];
}

// ---------------- LDS swizzled 16B K reads (chunk XOR to spread banks) -------------
__device__ __forceinline__ bf16x8 lds_swzK(const unsigned short* s, int row, int chunk) {
  int byte = row * 128 + ((chunk ^ ((row >> 2) & 7)) << 4);
  return *(const bf16x8*)((const char*)s + byte);
}

// ---------------- Flash attention, causal, exp2 softmax (no running max) ----------
// Block = 128 q rows (32/wave, mt=2), KV tiles of 64. K staged in LDS (swizzled);
// V fragments loaded directly from vT global (contiguous 16B/lane, natural kv order
// matches the P column permutation col = 4*ln + t). Mask only where the tile
// straddles the diagonal; waves entirely above a tile skip compute.
__global__ __launch_bounds__(256, 3) void flash_kernel(
    const unsigned short* __restrict__ qg, const unsigned short* __restrict__ kg,
    const unsigned short* __restrict__ vtg, unsigned short* __restrict__ attn) {
  __shared__ alignas(16) unsigned short sK[64 * 64];
  __shared__ alignas(16) unsigned short sP[4 * 32 * 72];  // per-wave 32x64, stride 72

  const int tid = threadIdx.x;
  const int lane = tid & 63, wave = tid >> 6;
  const int ln = lane & 15, quad = lane >> 4;
  const int h = blockIdx.y;
  const int qb = (int)(gridDim.x - 1 - blockIdx.x);  // longest blocks first
  const int q0 = qb * 128;
  const int qrow = q0 + wave * 32;

  const unsigned short* qh = qg + (size_t)h * (S_LEN * HD);
  const unsigned short* kh = kg + (size_t)h * (S_LEN * HD);
  const unsigned short* vh = vtg + (size_t)h * (HD * S_LEN);

  // Q fragments (A-layout: m=ln, k=quad*8+j), 32 rows/wave
  bf16x8 qf[2][2];
#pragma unroll
  for (int mt = 0; mt < 2; ++mt)
#pragma unroll
    for (int ks = 0; ks < 2; ++ks)
      qf[mt][ks] = *(const bf16x8*)(qh + (size_t)(qrow + mt * 16 + ln) * HD + ks * 32 + quad * 8);

  f32x4 o_acc[2][4];
  f32x4 l_acc[2];
#pragma unroll
  for (int mt = 0; mt < 2; ++mt) {
    l_acc[mt] = fzero4();
#pragma unroll
    for (int t = 0; t < 4; ++t) o_acc[mt][t] = fzero4();
  }
  bf16x8 ones;
#pragma unroll
  for (int j = 0; j < 8; ++j) ones[j] = (short)0x3F80;  // bf16 1.0

  unsigned short* pw = &sP[wave * (32 * 72)];
  const int nkv = 2 * qb + 2;

  for (int kt = 0; kt < nkv; ++kt) {
    const int kv0 = kt * 64;
    __syncthreads();  // protect sK from previous iteration's readers
#pragma unroll
    for (int i = 0; i < 2; ++i) {
      int ob = (i * 256 + tid) * 16;
      int row = ob >> 7;
      int ch = (ob >> 4) & 7;
      gload16(kh + (size_t)(kv0 + row) * HD + ((ch ^ ((row >> 2) & 7)) << 3), (char*)sK + ob);
    }
    __syncthreads();

    if (kv0 > qrow + 31) continue;  // wave entirely above this tile (P would be all-zero)

    // S = Q K^T (tile t col ln <-> kv row 4*ln+t)
    f32x4 sc[2][4];
#pragma unroll
    for (int mt = 0; mt < 2; ++mt)
#pragma unroll
      for (int t = 0; t < 4; ++t) sc[mt][t] = fzero4();
#pragma unroll
    for (int t = 0; t < 4; ++t) {
      int krow = ln * 4 + t;
      bf16x8 kb0 = lds_swzK(sK, krow, quad);
      bf16x8 kb1 = lds_swzK(sK, krow, 4 + quad);
#pragma unroll
      for (int mt = 0; mt < 2; ++mt) {
        sc[mt][t] = __builtin_amdgcn_mfma_f32_16x16x32_bf16(qf[mt][0], kb0, sc[mt][t], 0, 0, 0);
        sc[mt][t] = __builtin_amdgcn_mfma_f32_16x16x32_bf16(qf[mt][1], kb1, sc[mt][t], 0, 0, 0);
      }
    }

    // V fragments direct from global (row t*16+ln of vT, natural kv order = P col order)
    bf16x8 vb[4][2];
#pragma unroll
    for (int t = 0; t < 4; ++t) {
      const unsigned short* vrow = vh + (size_t)(t * 16 + ln) * S_LEN + kv0 + quad * 8;
      vb[t][0] = *(const bf16x8*)(vrow);
      vb[t][1] = *(const bf16x8*)(vrow + 32);
    }

    // p = exp2(s); mask only when tile straddles diagonal; truncation pack; b64 writes
    if (kv0 + 63 > qrow) {
#pragma unroll
      for (int mt = 0; mt < 2; ++mt)
#pragma unroll
        for (int r = 0; r < 4; ++r) {
          int row = qrow + mt * 16 + quad * 4 + r;
          int colb = kv0 + ln * 4;
          float p0 = (colb + 0 <= row) ? __builtin_amdgcn_exp2f(sc[mt][0][r]) : 0.0f;
          float p1 = (colb + 1 <= row) ? __builtin_amdgcn_exp2f(sc[mt][1][r]) : 0.0f;
          float p2 = (colb + 2 <= row) ? __builtin_amdgcn_exp2f(sc[mt][2][r]) : 0.0f;
          float p3 = (colb + 3 <= row) ? __builtin_amdgcn_exp2f(sc[mt][3][r]) : 0.0f;
          *(uint2*)&pw[(mt * 16 + quad * 4 + r) * 72 + ln * 4] =
              make_uint2(pk2t(p0, p1), pk2t(p2, p3));
        }
    } else {
#pragma unroll
      for (int mt = 0; mt < 2; ++mt)
#pragma unroll
        for (int r = 0; r < 4; ++r) {
          float p0 = __builtin_amdgcn_exp2f(sc[mt][0][r]);
          float p1 = __builtin_amdgcn_exp2f(sc[mt][1][r]);
          float p2 = __builtin_amdgcn_exp2f(sc[mt][2][r]);
          float p3 = __builtin_amdgcn_exp2f(sc[mt][3][r]);
          *(uint2*)&pw[(mt * 16 + quad * 4 + r) * 72 + ln * 4] =
              make_uint2(pk2t(p0, p1), pk2t(p2, p3));
        }
    }

    // P fragments (A-layout), per-wave region -> no barrier needed
    bf16x8 pa[2][2];
#pragma unroll
    for (int mt = 0; mt < 2; ++mt) {
      pa[mt][0] = *(const bf16x8*)&pw[(mt * 16 + ln) * 72 + quad * 8];
      pa[mt][1] = *(const bf16x8*)&pw[(mt * 16 + ln) * 72 + 32 + quad * 8];
    }

    // l += P @ ones
#pragma unroll
    for (int mt = 0; mt < 2; ++mt) {
      l_acc[mt] = __builtin_amdgcn_mfma_f32_16x16x32_bf16(pa[mt][0], ones, l_acc[mt], 0, 0, 0);
      l_acc[mt] = __builtin_amdgcn_mfma_f32_16x16x32_bf16(pa[mt][1], ones, l_acc[mt], 0, 0, 0);
    }

    // O += P @ V
#pragma unroll
    for (int t = 0; t < 4; ++t)
#pragma unroll
      for (int mt = 0; mt < 2; ++mt) {
        o_acc[mt][t] = __builtin_amdgcn_mfma_f32_16x16x32_bf16(pa[mt][0], vb[t][0], o_acc[mt][t], 0, 0, 0);
        o_acc[mt][t] = __builtin_amdgcn_mfma_f32_16x16x32_bf16(pa[mt][1], vb[t][1], o_acc[mt][t], 0, 0, 0);
      }
  }

  // epilogue: attn[s, h*64+hd] = O/l (bf16)
#pragma unroll
  for (int mt = 0; mt < 2; ++mt) {
    float inv[4];
#pragma unroll
    for (int r = 0; r < 4; ++r) inv[r] = 1.0f / l_acc[mt][r];
#pragma unroll
    for (int t = 0; t < 4; ++t)
#pragma unroll
      for (int r = 0; r < 4; ++r) {
        int row = qrow + mt * 16 + quad * 4 + r;
        attn[(size_t)row * DIM + h * HD + t * 16 + ln] = f2b(o_acc[mt][t][r] * inv[r]);
      }
  }
}

extern "C" void kernel_launch(void* const* d_in, const int* in_sizes, int n_in,
                              void* d_out, int out_size, void* d_ws, size_t ws_size,
                              hipStream_t stream) {
  const float* x    = (const float*)d_in[0];
  const float* fc   = (const float*)d_in[2];
  const float* fs   = (const float*)d_in[3];
  const float* wqw  = (const float*)d_in[5];
  const float* wqb  = (const float*)d_in[6];
  const float* wkw  = (const float*)d_in[7];
  const float* wkb  = (const float*)d_in[8];
  const float* wvw  = (const float*)d_in[9];
  const float* wvb  = (const float*)d_in[10];
  const float* wow  = (const float*)d_in[11];
  const float* wobf = (const float*)d_in[12];
  float* out = (float*)d_out;

  char* ws = (char*)d_ws;
  const size_t MB = (size_t)1 << 20;
  unsigned short* xb    = (unsigned short*)(ws + 0);
  unsigned short* wqkvb = (unsigned short*)(ws + 8 * MB);
  unsigned short* wobb  = (unsigned short*)(ws + 16 * MB);
  float* biasq = (float*)(ws + 18 * MB);
  float* biaso = (float*)(ws + 18 * MB + 65536);
  unsigned short* qb_ = (unsigned short*)(ws + 19 * MB);
  unsigned short* kb_ = (unsigned short*)(ws + 27 * MB);
  unsigned short* vb_ = (unsigned short*)(ws + 35 * MB);
  unsigned short* vt  = (unsigned short*)(ws + 8 * MB);  // aliases wqkvb (dead after QKV GEMM)
  unsigned short* attn = (unsigned short*)(ws + 0);      // aliases xb (dead after QKV GEMM)

  cvt_all<<<8196, 256, 0, stream>>>(x, wqw, wkw, wvw, wow, wqb, wkb, wvb, wobf,
                                    xb, wqkvb, wobb, biasq, biaso);
  gemm_nt<<<dim3(32, 24), 256, 0, stream>>>(xb, wqkvb, biasq, nullptr, qb_, kb_, vb_,
                                            4096, 3072, 1024, 0);
  rope_kernel<<<4096, 256, 0, stream>>>(qb_, kb_, fc, fs);
  transpose_v<<<dim3(64, 16), 256, 0, stream>>>(vb_, vt);
  flash_kernel<<<dim3(32, 16), 256, 0, stream>>>(qb_, kb_, vt, attn);
  gemm_nt<<<dim3(32, 8), 256, 0, stream>>>(attn, wobb, biaso, out, nullptr, nullptr, nullptr,
                                           4096, 1024, 1024, 1);
}

// Round 4
// 357.812 us; speedup vs baseline: 1.0210x; 1.0210x over previous
//
#include <hip/hip_runtime.h>

// AttentionLoRA: B=1, S=4096, D=1024, H=16, HD=64.
// Pipeline: cvt_all(f32->bf16 + bias pack) -> QKV NT-GEMM (ping-pong staged, scatter
// epilogue) -> RoPE (q pre-scaled by 0.125*log2e) -> V transpose -> flash attention
// (64-row q blocks, complementary-qb swizzle for CU balance, ping-pong K in LDS with
//  post-barrier DMA issue, V register-fragments from global, exp2 softmax, no running
//  max) -> out-proj GEMM (f32 out).

#define S_LEN 4096
#define DIM   1024
#define NH    16
#define HD    64

typedef __attribute__((ext_vector_type(8))) short bf16x8;   // 8 bf16 = 4 VGPRs
typedef __attribute__((ext_vector_type(4))) float f32x4;

__device__ __forceinline__ unsigned short f2b(float f) {
  union { float f; unsigned int u; } v; v.f = f;
  unsigned int r = (v.u + 0x7fffu + ((v.u >> 16) & 1u)) >> 16;  // RNE
  return (unsigned short)r;
}
__device__ __forceinline__ float b2f(unsigned short h) {
  union { unsigned int u; float f; } v; v.u = ((unsigned int)h) << 16;
  return v.f;
}
// pack two f32 -> two bf16 by truncation (p in [0,1]; <=1ulp)
__device__ __forceinline__ unsigned int pk2t(float a, float b) {
  union { float f; unsigned int u; } x, y; x.f = a; y.f = b;
  return (x.u >> 16) | (y.u & 0xffff0000u);
}
__device__ __forceinline__ void gload16(const void* g, void* l) {
  __builtin_amdgcn_global_load_lds(
      (const __attribute__((address_space(1))) unsigned int*)g,
      (__attribute__((address_space(3))) unsigned int*)l, 16, 0, 0);
}
__device__ __forceinline__ f32x4 fzero4() { f32x4 z = {0.f, 0.f, 0.f, 0.f}; return z; }

// ---------------- fused f32->bf16 convert (x, wq, wk, wv, wo) + bias pack ----------
__global__ void cvt_all(const float* __restrict__ x, const float* __restrict__ wq,
                        const float* __restrict__ wk, const float* __restrict__ wv,
                        const float* __restrict__ wo, const float* __restrict__ qb,
                        const float* __restrict__ kb, const float* __restrict__ vbs,
                        const float* __restrict__ ob, unsigned short* __restrict__ xb,
                        unsigned short* __restrict__ wqkvb, unsigned short* __restrict__ wobb,
                        float* __restrict__ biasq, float* __restrict__ biaso) {
  int i = blockIdx.x * 256 + threadIdx.x;  // float4 index
  if (i < 2097152) {
    const float* src; unsigned short* dst; int off;
    if (i < 1048576)      { src = x;  dst = xb;              off = i; }
    else if (i < 1310720) { src = wq; dst = wqkvb;           off = i - 1048576; }
    else if (i < 1572864) { src = wk; dst = wqkvb + 1048576; off = i - 1310720; }
    else if (i < 1835008) { src = wv; dst = wqkvb + 2097152; off = i - 1572864; }
    else                  { src = wo; dst = wobb;            off = i - 1835008; }
    float4 v = ((const float4*)src)[off];
    unsigned int lo = (unsigned int)f2b(v.x) | ((unsigned int)f2b(v.y) << 16);
    unsigned int hi = (unsigned int)f2b(v.z) | ((unsigned int)f2b(v.w) << 16);
    ((uint2*)dst)[off] = make_uint2(lo, hi);
  } else if (i < 2097152 + 1024) {
    int j = i - 2097152;
    if (j < 256)      ((float4*)biasq)[j]              = ((const float4*)qb)[j];
    else if (j < 512) ((float4*)(biasq + 1024))[j-256] = ((const float4*)kb)[j-256];
    else if (j < 768) ((float4*)(biasq + 2048))[j-512] = ((const float4*)vbs)[j-512];
    else              ((float4*)biaso)[j-768]          = ((const float4*)ob)[j-768];
  }
}

// ---------------- NT GEMM: C[m,n] = sum_k A[m,k]*B[n,k] + bias[n] ----------------
// 128x128 tile, BK=32, 4 waves each 64x64 (4x4 of 16x16x32 MFMA). Ping-pong LDS
// staging: one barrier per K-iter; the global_load_lds for iter t+1 is issued AFTER
// the barrier of iter t, so its drain (at barrier t+1) is hidden by tile-t compute.
// mode 0: scatter to q/k/v bf16 (h,s,hd).  mode 1: f32 row-major out.
__global__ __launch_bounds__(256) void gemm_nt(
    const unsigned short* __restrict__ A, const unsigned short* __restrict__ B,
    const float* __restrict__ bias, float* __restrict__ outF,
    unsigned short* __restrict__ dq, unsigned short* __restrict__ dk,
    unsigned short* __restrict__ dv, int M, int N, int K, int mode) {
  __shared__ alignas(16) unsigned short sA[2][128 * 32];
  __shared__ alignas(16) unsigned short sB[2][128 * 32];
  const int tid = threadIdx.x;
  const int lane = tid & 63, wave = tid >> 6;
  const int ln = lane & 15, quad = lane >> 4;
  const int bm = blockIdx.x * 128, bn = blockIdx.y * 128;
  const int wr = (wave >> 1) * 64, wc = (wave & 1) * 64;

  f32x4 acc[4][4];
#pragma unroll
  for (int i = 0; i < 4; ++i)
#pragma unroll
    for (int j = 0; j < 4; ++j) acc[i][j] = fzero4();

  // preload K-tile 0 into buffer 0
#pragma unroll
  for (int i = 0; i < 2; ++i) {
    int o = (i * 256 + tid) * 16;
    int e = o >> 1;
    int row = e >> 5, col = e & 31;
    gload16(A + (size_t)(bm + row) * K + col, (char*)sA[0] + o);
    gload16(B + (size_t)(bn + row) * K + col, (char*)sB[0] + o);
  }

  int buf = 0;
  for (int k0 = 0; k0 < K; k0 += 32, buf ^= 1) {
    __syncthreads();  // drains DMA for current buf; guards other buf vs old readers
    if (k0 + 32 < K) {
#pragma unroll
      for (int i = 0; i < 2; ++i) {
        int o = (i * 256 + tid) * 16;
        int e = o >> 1;
        int row = e >> 5, col = e & 31;
        gload16(A + (size_t)(bm + row) * K + k0 + 32 + col, (char*)sA[buf ^ 1] + o);
        gload16(B + (size_t)(bn + row) * K + k0 + 32 + col, (char*)sB[buf ^ 1] + o);
      }
    }
    bf16x8 af[4], bfr[4];
#pragma unroll
    for (int i = 0; i < 4; ++i) {
      af[i]  = *(const bf16x8*)&sA[buf][(wr + i * 16 + ln) * 32 + quad * 8];
      bfr[i] = *(const bf16x8*)&sB[buf][(wc + i * 16 + ln) * 32 + quad * 8];
    }
#pragma unroll
    for (int i = 0; i < 4; ++i)
#pragma unroll
      for (int j = 0; j < 4; ++j)
        acc[i][j] = __builtin_amdgcn_mfma_f32_16x16x32_bf16(af[i], bfr[j], acc[i][j], 0, 0, 0);
  }

  if (mode == 1) {
#pragma unroll
    for (int i = 0; i < 4; ++i)
#pragma unroll
      for (int j = 0; j < 4; ++j) {
        int n = bn + wc + j * 16 + ln;
        float bi = bias[n];
#pragma unroll
        for (int r = 0; r < 4; ++r) {
          int m = bm + wr + i * 16 + quad * 4 + r;
          outF[(size_t)m * N + n] = acc[i][j][r] + bi;
        }
      }
  } else {
    const int bufi = bn >> 10;
    unsigned short* const base = bufi == 0 ? dq : (bufi == 1 ? dk : dv);
    const int hq = ((bn & 1023) + wc) >> 6;  // head index, wave-uniform
#pragma unroll
    for (int i = 0; i < 4; ++i)
#pragma unroll
      for (int j = 0; j < 4; ++j) {
        int n = bn + wc + j * 16 + ln;
        float bi = bias[n];
        int hd = j * 16 + ln;
#pragma unroll
        for (int r = 0; r < 4; ++r) {
          int m = bm + wr + i * 16 + quad * 4 + r;
          base[((size_t)(hq * S_LEN + m)) * HD + hd] = f2b(acc[i][j][r] + bi);
        }
      }
  }
}

// ---------------- RoPE in-place on q,k (h,s,hd); q pre-scaled by 0.125*log2e ------
__global__ void rope_kernel(unsigned short* __restrict__ q, unsigned short* __restrict__ k,
                            const float* __restrict__ fc, const float* __restrict__ fs) {
  int idx = blockIdx.x * 256 + threadIdx.x;  // 2 * 16*4096*8
  const int P = NH * S_LEN * 8;
  bool isq = idx < P;
  unsigned short* t = isq ? q : k;
  int i = isq ? idx : idx - P;
  int g = i & 7;
  int s = (i >> 3) & 4095;
  int h = i >> 15;
  const float scale = isq ? 0.180336880f : 1.0f;  // (1/8)*log2(e) folded into q
  float4 c4 = *(const float4*)&fc[s * 32 + g * 4];
  float4 s4 = *(const float4*)&fs[s * 32 + g * 4];
  uint4* p = (uint4*)&t[((size_t)(h * S_LEN + s)) * HD + g * 8];
  uint4 pv = *p;
  auto rot = [&](unsigned int w, float c, float sn) -> unsigned int {
    float x0 = b2f((unsigned short)(w & 0xffffu));
    float x1 = b2f((unsigned short)(w >> 16));
    float o0 = (x0 * c - x1 * sn) * scale;
    float o1 = (x0 * sn + x1 * c) * scale;
    return (unsigned int)f2b(o0) | ((unsigned int)f2b(o1) << 16);
  };
  pv.x = rot(pv.x, c4.x, s4.x);
  pv.y = rot(pv.y, c4.y, s4.y);
  pv.z = rot(pv.z, c4.z, s4.z);
  pv.w = rot(pv.w, c4.w, s4.w);
  *p = pv;
}

// ---------------- V transpose: (h,s,hd) -> (h,hd,s) ----------------
__global__ void transpose_v(const unsigned short* __restrict__ v, unsigned short* __restrict__ vt) {
  __shared__ unsigned short t[64][65];
  const int h = blockIdx.y;
  const int s0 = blockIdx.x * 64;
  const int tid = threadIdx.x;
  const int r = tid >> 2, c0 = (tid & 3) * 16;
  const unsigned short* src = v + ((size_t)h * S_LEN + s0 + r) * HD + c0;
#pragma unroll
  for (int j = 0; j < 16; ++j) t[r][c0 + j] = src[j];
  __syncthreads();
  unsigned short* dst = vt + ((size_t)h * HD + r) * S_LEN + s0 + c0;
#pragma unroll
  for (int j = 0; j < 16; ++j) dst[j] = t[c0 + j][r];
}

// ---------------- LDS swizzled 16B K reads (chunk XOR to spread banks) -------------
__device__ __forceinline__ bf16x8 lds_swzK(const unsigned short* s, int row, int chunk) {
  int byte = row * 128 + ((chunk ^ ((row >> 2) & 7)) << 4);
  return *(const bf16x8*)((const char*)s + byte);
}

// ---------------- Flash attention, causal, exp2 softmax (no running max) ----------
// Block = 64 q rows (16/wave), KV tiles of 64, grid (64, 16).
// qb swizzle: blocks c and c+256 (same CU under round-robin dispatch) get
// complementary qb -> every CU totals 130 tile-steps (perfect static balance).
// K ping-pong staged in LDS; the DMA for tile t+1 issues AFTER barrier t, so its
// drain (at barrier t+1) is hidden by tile-t compute. V fragments are plain global
// loads from vT (not drained by barriers), issued at tile top, consumed ~400cyc
// later by PV. Score col ln of tile t <-> kv row 4*ln+t (P writes = b64/lane).
// Mask only on the diagonal tile. l via MFMA-with-ones (same C-layout as O).
__global__ __launch_bounds__(256, 3) void flash_kernel(
    const unsigned short* __restrict__ qg, const unsigned short* __restrict__ kg,
    const unsigned short* __restrict__ vtg, unsigned short* __restrict__ attn) {
  __shared__ alignas(16) unsigned short sK[2][64 * 64];
  __shared__ alignas(16) unsigned short sP[4 * 16 * 72];  // per-wave 16x64, stride 72

  const int tid = threadIdx.x;
  const int lane = tid & 63, wave = tid >> 6;
  const int ln = lane & 15, quad = lane >> 4;
  const int h = blockIdx.y;
  const int x = blockIdx.x;
  const int qb = ((h >> 2) & 1) ? x : 63 - x;  // complementary pairing across CUs
  const int q0 = qb * 64;
  const int qrow = q0 + wave * 16;

  const unsigned short* qh = qg + (size_t)h * (S_LEN * HD);
  const unsigned short* kh = kg + (size_t)h * (S_LEN * HD);
  const unsigned short* vh = vtg + (size_t)h * (HD * S_LEN);

  bf16x8 qf[2];
  qf[0] = *(const bf16x8*)(qh + (size_t)(qrow + ln) * HD + quad * 8);
  qf[1] = *(const bf16x8*)(qh + (size_t)(qrow + ln) * HD + 32 + quad * 8);

  f32x4 o_acc[4];
  f32x4 l_acc = fzero4();
#pragma unroll
  for (int t = 0; t < 4; ++t) o_acc[t] = fzero4();
  bf16x8 ones;
#pragma unroll
  for (int j = 0; j < 8; ++j) ones[j] = (short)0x3F80;  // bf16 1.0

  unsigned short* pw = &sP[wave * (16 * 72)];
  const int nkv = qb + 1;

  // preload K tile 0 into buffer 0 (swizzled rows)
#pragma unroll
  for (int i = 0; i < 2; ++i) {
    int ob = (i * 256 + tid) * 16;
    int row = ob >> 7;
    int ch = (ob >> 4) & 7;
    gload16(kh + (size_t)row * HD + ((ch ^ ((row >> 2) & 7)) << 3), (char*)sK[0] + ob);
  }

  int buf = 0;
  for (int kt = 0; kt < nkv; ++kt, buf ^= 1) {
    const int kv0 = kt * 64;
    __syncthreads();  // drains K(kt) DMA (issued a full tile ago); guards other buf
    if (kt + 1 < nkv) {
      const int kv1 = kv0 + 64;
#pragma unroll
      for (int i = 0; i < 2; ++i) {
        int ob = (i * 256 + tid) * 16;
        int row = ob >> 7;
        int ch = (ob >> 4) & 7;
        gload16(kh + (size_t)(kv1 + row) * HD + ((ch ^ ((row >> 2) & 7)) << 3),
                (char*)sK[buf ^ 1] + ob);
      }
    }

    // V fragments direct from global (plain VGPR loads, not drained by barriers);
    // issued here, consumed after QK+exp (~400 cyc) -> L2 latency hidden.
    bf16x8 vb[4][2];
#pragma unroll
    for (int t = 0; t < 4; ++t) {
      const unsigned short* vrow = vh + (size_t)(t * 16 + ln) * S_LEN + kv0 + quad * 8;
      vb[t][0] = *(const bf16x8*)(vrow);
      vb[t][1] = *(const bf16x8*)(vrow + 32);
    }

    // S = Q K^T (tile t col ln <-> kv row 4*ln+t)
    const unsigned short* kb_ptr = sK[buf];
    f32x4 sc[4];
#pragma unroll
    for (int t = 0; t < 4; ++t) sc[t] = fzero4();
#pragma unroll
    for (int t = 0; t < 4; ++t) {
      int krow = ln * 4 + t;
      bf16x8 kb0 = lds_swzK(kb_ptr, krow, quad);
      bf16x8 kb1 = lds_swzK(kb_ptr, krow, 4 + quad);
      sc[t] = __builtin_amdgcn_mfma_f32_16x16x32_bf16(qf[0], kb0, sc[t], 0, 0, 0);
      sc[t] = __builtin_amdgcn_mfma_f32_16x16x32_bf16(qf[1], kb1, sc[t], 0, 0, 0);
    }

    // p = exp2(s); mask only on diagonal tile; truncation pack; b64 LDS writes
    if (kt == nkv - 1) {
#pragma unroll
      for (int r = 0; r < 4; ++r) {
        int row = qrow + quad * 4 + r;
        int colb = kv0 + ln * 4;
        float p0 = (colb + 0 <= row) ? __builtin_amdgcn_exp2f(sc[0][r]) : 0.0f;
        float p1 = (colb + 1 <= row) ? __builtin_amdgcn_exp2f(sc[1][r]) : 0.0f;
        float p2 = (colb + 2 <= row) ? __builtin_amdgcn_exp2f(sc[2][r]) : 0.0f;
        float p3 = (colb + 3 <= row) ? __builtin_amdgcn_exp2f(sc[3][r]) : 0.0f;
        *(uint2*)&pw[(quad * 4 + r) * 72 + ln * 4] = make_uint2(pk2t(p0, p1), pk2t(p2, p3));
      }
    } else {
#pragma unroll
      for (int r = 0; r < 4; ++r) {
        float p0 = __builtin_amdgcn_exp2f(sc[0][r]);
        float p1 = __builtin_amdgcn_exp2f(sc[1][r]);
        float p2 = __builtin_amdgcn_exp2f(sc[2][r]);
        float p3 = __builtin_amdgcn_exp2f(sc[3][r]);
        *(uint2*)&pw[(quad * 4 + r) * 72 + ln * 4] = make_uint2(pk2t(p0, p1), pk2t(p2, p3));
      }
    }

    // P fragments (A-layout), per-wave region -> no barrier needed
    bf16x8 pa0 = *(const bf16x8*)&pw[ln * 72 + quad * 8];
    bf16x8 pa1 = *(const bf16x8*)&pw[ln * 72 + 32 + quad * 8];

    // l += P @ ones
    l_acc = __builtin_amdgcn_mfma_f32_16x16x32_bf16(pa0, ones, l_acc, 0, 0, 0);
    l_acc = __builtin_amdgcn_mfma_f32_16x16x32_bf16(pa1, ones, l_acc, 0, 0, 0);

    // O += P @ V
#pragma unroll
    for (int t = 0; t < 4; ++t) {
      o_acc[t] = __builtin_amdgcn_mfma_f32_16x16x32_bf16(pa0, vb[t][0], o_acc[t], 0, 0, 0);
      o_acc[t] = __builtin_amdgcn_mfma_f32_16x16x32_bf16(pa1, vb[t][1], o_acc[t], 0, 0, 0);
    }
  }

  // epilogue: attn[s, h*64+hd] = O/l (bf16)
  float inv[4];
#pragma unroll
  for (int r = 0; r < 4; ++r) inv[r] = 1.0f / l_acc[r];
#pragma unroll
  for (int t = 0; t < 4; ++t)
#pragma unroll
    for (int r = 0; r < 4; ++r) {
      int row = qrow + quad * 4 + r;
      attn[(size_t)row * DIM + h * HD + t * 16 + ln] = f2b(o_acc[t][r] * inv[r]);
    }
}

extern "C" void kernel_launch(void* const* d_in, const int* in_sizes, int n_in,
                              void* d_out, int out_size, void* d_ws, size_t ws_size,
                              hipStream_t stream) {
  const float* x    = (const float*)d_in[0];
  const float* fc   = (const float*)d_in[2];
  const float* fs   = (const float*)d_in[3];
  const float* wqw  = (const float*)d_in[5];
  const float* wqb  = (const float*)d_in[6];
  const float* wkw  = (const float*)d_in[7];
  const float* wkb  = (const float*)d_in[8];
  const float* wvw  = (const float*)d_in[9];
  const float* wvb  = (const float*)d_in[10];
  const float* wow  = (const float*)d_in[11];
  const float* wobf = (const float*)d_in[12];
  float* out = (float*)d_out;

  char* ws = (char*)d_ws;
  const size_t MB = (size_t)1 << 20;
  unsigned short* xb    = (unsigned short*)(ws + 0);
  unsigned short* wqkvb = (unsigned short*)(ws + 8 * MB);
  unsigned short* wobb  = (unsigned short*)(ws + 16 * MB);
  float* biasq = (float*)(ws + 18 * MB);
  float* biaso = (float*)(ws + 18 * MB + 65536);
  unsigned short* qb_ = (unsigned short*)(ws + 19 * MB);
  unsigned short* kb_ = (unsigned short*)(ws + 27 * MB);
  unsigned short* vb_ = (unsigned short*)(ws + 35 * MB);
  unsigned short* vt  = (unsigned short*)(ws + 8 * MB);  // aliases wqkvb (dead after QKV GEMM)
  unsigned short* attn = (unsigned short*)(ws + 0);      // aliases xb (dead after QKV GEMM)

  cvt_all<<<8196, 256, 0, stream>>>(x, wqw, wkw, wvw, wow, wqb, wkb, wvb, wobf,
                                    xb, wqkvb, wobb, biasq, biaso);
  gemm_nt<<<dim3(32, 24), 256, 0, stream>>>(xb, wqkvb, biasq, nullptr, qb_, kb_, vb_,
                                            4096, 3072, 1024, 0);
  rope_kernel<<<4096, 256, 0, stream>>>(qb_, kb_, fc, fs);
  transpose_v<<<dim3(64, 16), 256, 0, stream>>>(vb_, vt);
  flash_kernel<<<dim3(64, 16), 256, 0, stream>>>(qb_, kb_, vt, attn);
  gemm_nt<<<dim3(32, 8), 256, 0, stream>>>(attn, wobb, biaso, out, nullptr, nullptr, nullptr,
                                           4096, 1024, 1024, 1);
}

// Round 5
// 281.225 us; speedup vs baseline: 1.2991x; 1.2723x over previous
//
#include <hip/hip_runtime.h>

// AttentionLoRA: B=1, S=4096, D=1024, H=16, HD=64.
// Pipeline: cvt_all(f32->bf16 + bias pack) -> QKV NT-GEMM (ping-pong staged, scatter
// epilogue) -> RoPE (q pre-scaled by 0.125*log2e) -> V transpose -> flash attention
// (64-row q blocks, complementary-qb swizzle, K+V DMA-staged in LDS [R2 structure:
//  V-from-global gather was the R3/R4 regression], exp2 softmax, no running max)
// -> out-proj GEMM (f32 out).

#define S_LEN 4096
#define DIM   1024
#define NH    16
#define HD    64

typedef __attribute__((ext_vector_type(8))) short bf16x8;   // 8 bf16 = 4 VGPRs
typedef __attribute__((ext_vector_type(4))) float f32x4;

__device__ __forceinline__ unsigned short f2b(float f) {
  union { float f; unsigned int u; } v; v.f = f;
  unsigned int r = (v.u + 0x7fffu + ((v.u >> 16) & 1u)) >> 16;  // RNE
  return (unsigned short)r;
}
__device__ __forceinline__ float b2f(unsigned short h) {
  union { unsigned int u; float f; } v; v.u = ((unsigned int)h) << 16;
  return v.f;
}
// pack two f32 -> two bf16 by truncation (p in [0,1]; <=1ulp)
__device__ __forceinline__ unsigned int pk2t(float a, float b) {
  union { float f; unsigned int u; } x, y; x.f = a; y.f = b;
  return (x.u >> 16) | (y.u & 0xffff0000u);
}
__device__ __forceinline__ void gload16(const void* g, void* l) {
  __builtin_amdgcn_global_load_lds(
      (const __attribute__((address_space(1))) unsigned int*)g,
      (__attribute__((address_space(3))) unsigned int*)l, 16, 0, 0);
}
__device__ __forceinline__ f32x4 fzero4() { f32x4 z = {0.f, 0.f, 0.f, 0.f}; return z; }

// ---------------- fused f32->bf16 convert (x, wq, wk, wv, wo) + bias pack ----------
__global__ void cvt_all(const float* __restrict__ x, const float* __restrict__ wq,
                        const float* __restrict__ wk, const float* __restrict__ wv,
                        const float* __restrict__ wo, const float* __restrict__ qb,
                        const float* __restrict__ kb, const float* __restrict__ vbs,
                        const float* __restrict__ ob, unsigned short* __restrict__ xb,
                        unsigned short* __restrict__ wqkvb, unsigned short* __restrict__ wobb,
                        float* __restrict__ biasq, float* __restrict__ biaso) {
  int i = blockIdx.x * 256 + threadIdx.x;  // float4 index
  if (i < 2097152) {
    const float* src; unsigned short* dst; int off;
    if (i < 1048576)      { src = x;  dst = xb;              off = i; }
    else if (i < 1310720) { src = wq; dst = wqkvb;           off = i - 1048576; }
    else if (i < 1572864) { src = wk; dst = wqkvb + 1048576; off = i - 1310720; }
    else if (i < 1835008) { src = wv; dst = wqkvb + 2097152; off = i - 1572864; }
    else                  { src = wo; dst = wobb;            off = i - 1835008; }
    float4 v = ((const float4*)src)[off];
    unsigned int lo = (unsigned int)f2b(v.x) | ((unsigned int)f2b(v.y) << 16);
    unsigned int hi = (unsigned int)f2b(v.z) | ((unsigned int)f2b(v.w) << 16);
    ((uint2*)dst)[off] = make_uint2(lo, hi);
  } else if (i < 2097152 + 1024) {
    int j = i - 2097152;
    if (j < 256)      ((float4*)biasq)[j]              = ((const float4*)qb)[j];
    else if (j < 512) ((float4*)(biasq + 1024))[j-256] = ((const float4*)kb)[j-256];
    else if (j < 768) ((float4*)(biasq + 2048))[j-512] = ((const float4*)vbs)[j-512];
    else              ((float4*)biaso)[j-768]          = ((const float4*)ob)[j-768];
  }
}

// ---------------- NT GEMM: C[m,n] = sum_k A[m,k]*B[n,k] + bias[n] ----------------
// 128x128 tile, BK=32, 4 waves each 64x64 (4x4 of 16x16x32 MFMA). Ping-pong LDS
// staging, one barrier per K-iter (DMA for t+1 issued after barrier t).
// mode 0: scatter to q/k/v bf16 (h,s,hd).  mode 1: f32 row-major out.
__global__ __launch_bounds__(256) void gemm_nt(
    const unsigned short* __restrict__ A, const unsigned short* __restrict__ B,
    const float* __restrict__ bias, float* __restrict__ outF,
    unsigned short* __restrict__ dq, unsigned short* __restrict__ dk,
    unsigned short* __restrict__ dv, int M, int N, int K, int mode) {
  __shared__ alignas(16) unsigned short sA[2][128 * 32];
  __shared__ alignas(16) unsigned short sB[2][128 * 32];
  const int tid = threadIdx.x;
  const int lane = tid & 63, wave = tid >> 6;
  const int ln = lane & 15, quad = lane >> 4;
  const int bm = blockIdx.x * 128, bn = blockIdx.y * 128;
  const int wr = (wave >> 1) * 64, wc = (wave & 1) * 64;

  f32x4 acc[4][4];
#pragma unroll
  for (int i = 0; i < 4; ++i)
#pragma unroll
    for (int j = 0; j < 4; ++j) acc[i][j] = fzero4();

  // preload K-tile 0 into buffer 0
#pragma unroll
  for (int i = 0; i < 2; ++i) {
    int o = (i * 256 + tid) * 16;
    int e = o >> 1;
    int row = e >> 5, col = e & 31;
    gload16(A + (size_t)(bm + row) * K + col, (char*)sA[0] + o);
    gload16(B + (size_t)(bn + row) * K + col, (char*)sB[0] + o);
  }

  int buf = 0;
  for (int k0 = 0; k0 < K; k0 += 32, buf ^= 1) {
    __syncthreads();  // drains DMA for current buf; guards other buf vs old readers
    if (k0 + 32 < K) {
#pragma unroll
      for (int i = 0; i < 2; ++i) {
        int o = (i * 256 + tid) * 16;
        int e = o >> 1;
        int row = e >> 5, col = e & 31;
        gload16(A + (size_t)(bm + row) * K + k0 + 32 + col, (char*)sA[buf ^ 1] + o);
        gload16(B + (size_t)(bn + row) * K + k0 + 32 + col, (char*)sB[buf ^ 1] + o);
      }
    }
    bf16x8 af[4], bfr[4];
#pragma unroll
    for (int i = 0; i < 4; ++i) {
      af[i]  = *(const bf16x8*)&sA[buf][(wr + i * 16 + ln) * 32 + quad * 8];
      bfr[i] = *(const bf16x8*)&sB[buf][(wc + i * 16 + ln) * 32 + quad * 8];
    }
#pragma unroll
    for (int i = 0; i < 4; ++i)
#pragma unroll
      for (int j = 0; j < 4; ++j)
        acc[i][j] = __builtin_amdgcn_mfma_f32_16x16x32_bf16(af[i], bfr[j], acc[i][j], 0, 0, 0);
  }

  if (mode == 1) {
#pragma unroll
    for (int i = 0; i < 4; ++i)
#pragma unroll
      for (int j = 0; j < 4; ++j) {
        int n = bn + wc + j * 16 + ln;
        float bi = bias[n];
#pragma unroll
        for (int r = 0; r < 4; ++r) {
          int m = bm + wr + i * 16 + quad * 4 + r;
          outF[(size_t)m * N + n] = acc[i][j][r] + bi;
        }
      }
  } else {
    const int bufi = bn >> 10;
    unsigned short* const base = bufi == 0 ? dq : (bufi == 1 ? dk : dv);
    const int hq = ((bn & 1023) + wc) >> 6;  // head index, wave-uniform
#pragma unroll
    for (int i = 0; i < 4; ++i)
#pragma unroll
      for (int j = 0; j < 4; ++j) {
        int n = bn + wc + j * 16 + ln;
        float bi = bias[n];
        int hd = j * 16 + ln;
#pragma unroll
        for (int r = 0; r < 4; ++r) {
          int m = bm + wr + i * 16 + quad * 4 + r;
          base[((size_t)(hq * S_LEN + m)) * HD + hd] = f2b(acc[i][j][r] + bi);
        }
      }
  }
}

// ---------------- RoPE in-place on q,k (h,s,hd); q pre-scaled by 0.125*log2e ------
__global__ void rope_kernel(unsigned short* __restrict__ q, unsigned short* __restrict__ k,
                            const float* __restrict__ fc, const float* __restrict__ fs) {
  int idx = blockIdx.x * 256 + threadIdx.x;  // 2 * 16*4096*8
  const int P = NH * S_LEN * 8;
  bool isq = idx < P;
  unsigned short* t = isq ? q : k;
  int i = isq ? idx : idx - P;
  int g = i & 7;
  int s = (i >> 3) & 4095;
  int h = i >> 15;
  const float scale = isq ? 0.180336880f : 1.0f;  // (1/8)*log2(e) folded into q
  float4 c4 = *(const float4*)&fc[s * 32 + g * 4];
  float4 s4 = *(const float4*)&fs[s * 32 + g * 4];
  uint4* p = (uint4*)&t[((size_t)(h * S_LEN + s)) * HD + g * 8];
  uint4 pv = *p;
  auto rot = [&](unsigned int w, float c, float sn) -> unsigned int {
    float x0 = b2f((unsigned short)(w & 0xffffu));
    float x1 = b2f((unsigned short)(w >> 16));
    float o0 = (x0 * c - x1 * sn) * scale;
    float o1 = (x0 * sn + x1 * c) * scale;
    return (unsigned int)f2b(o0) | ((unsigned int)f2b(o1) << 16);
  };
  pv.x = rot(pv.x, c4.x, s4.x);
  pv.y = rot(pv.y, c4.y, s4.y);
  pv.z = rot(pv.z, c4.z, s4.z);
  pv.w = rot(pv.w, c4.w, s4.w);
  *p = pv;
}

// ---------------- V transpose: (h,s,hd) -> (h,hd,s) ----------------
__global__ void transpose_v(const unsigned short* __restrict__ v, unsigned short* __restrict__ vt) {
  __shared__ unsigned short t[64][65];
  const int h = blockIdx.y;
  const int s0 = blockIdx.x * 64;
  const int tid = threadIdx.x;
  const int r = tid >> 2, c0 = (tid & 3) * 16;
  const unsigned short* src = v + ((size_t)h * S_LEN + s0 + r) * HD + c0;
#pragma unroll
  for (int j = 0; j < 16; ++j) t[r][c0 + j] = src[j];
  __syncthreads();
  unsigned short* dst = vt + ((size_t)h * HD + r) * S_LEN + s0 + c0;
#pragma unroll
  for (int j = 0; j < 16; ++j) dst[j] = t[c0 + j][r];
}

// ---------------- LDS swizzled 16B reads (chunk XOR to spread banks) ----------------
__device__ __forceinline__ bf16x8 lds_swzK(const unsigned short* s, int row, int chunk) {
  int byte = row * 128 + ((chunk ^ ((row >> 2) & 7)) << 4);
  return *(const bf16x8*)((const char*)s + byte);
}
__device__ __forceinline__ bf16x8 lds_swzV(const unsigned short* s, int row, int chunk) {
  int byte = row * 128 + ((chunk ^ (row & 7)) << 4);
  return *(const bf16x8*)((const char*)s + byte);
}

// ---------------- Flash attention, causal, exp2 softmax (no running max) ----------
// R2 structure (the measured-fastest): K AND V DMA-staged into LDS each tile
// (coalesced rows, loaded once per block, shared by 4 waves) — per-wave V global
// gather (R3/R4) was the regression: 16-line strided lookups on the critical path.
// Block = 64 q rows (16/wave), KV tiles of 64, grid (64,16).
// ONE new variable vs R2: complementary qb swizzle — blocks c and c+256 (same CU
// under round-robin) get complementary lengths -> every CU ~130 tile-steps
// (R2's linear mapping gave one CU 4x the longest blocks -> 256-step makespan).
// Score col ln of tile t <-> kv row 4*ln+t (P writes contiguous b64/lane).
// Mask only on the diagonal tile. l via MFMA-with-ones (same C-layout as O).
__global__ __launch_bounds__(256, 4) void flash_kernel(
    const unsigned short* __restrict__ qg, const unsigned short* __restrict__ kg,
    const unsigned short* __restrict__ vtg, unsigned short* __restrict__ attn) {
  __shared__ alignas(16) unsigned short sK[64 * 64];
  __shared__ alignas(16) unsigned short sV[64 * 64];
  __shared__ alignas(16) unsigned short sP[4 * 16 * 72];  // per-wave 16x64, stride 72

  const int tid = threadIdx.x;
  const int lane = tid & 63, wave = tid >> 6;
  const int ln = lane & 15, quad = lane >> 4;
  const int h = blockIdx.y;
  const int qb = ((h >> 2) & 1) ? (int)blockIdx.x : 63 - (int)blockIdx.x;
  const int q0 = qb * 64;
  const int qrow = q0 + wave * 16;

  const unsigned short* qh = qg + (size_t)h * (S_LEN * HD);
  const unsigned short* kh = kg + (size_t)h * (S_LEN * HD);
  const unsigned short* vh = vtg + (size_t)h * (HD * S_LEN);

  bf16x8 qf[2];
  qf[0] = *(const bf16x8*)(qh + (size_t)(qrow + ln) * HD + quad * 8);
  qf[1] = *(const bf16x8*)(qh + (size_t)(qrow + ln) * HD + 32 + quad * 8);

  f32x4 o_acc[4];
  f32x4 l_acc = fzero4();
#pragma unroll
  for (int t = 0; t < 4; ++t) o_acc[t] = fzero4();
  bf16x8 ones;
#pragma unroll
  for (int j = 0; j < 8; ++j) ones[j] = (short)0x3F80;  // bf16 1.0

  unsigned short* pw = &sP[wave * (16 * 72)];
  const int nkv = qb + 1;

  for (int kt = 0; kt < nkv; ++kt) {
    const int kv0 = kt * 64;
    __syncthreads();  // protect sK/sV from previous iteration's readers
#pragma unroll
    for (int i = 0; i < 2; ++i) {
      int ob = (i * 256 + tid) * 16;
      int row = ob >> 7;
      int ch = (ob >> 4) & 7;
      gload16(kh + (size_t)(kv0 + row) * HD + ((ch ^ ((row >> 2) & 7)) << 3), (char*)sK + ob);
      gload16(vh + (size_t)row * S_LEN + kv0 + ((ch ^ (row & 7)) << 3), (char*)sV + ob);
    }
    __syncthreads();

    // S = Q K^T (tile t col ln <-> kv row 4*ln+t)
    f32x4 sc[4];
#pragma unroll
    for (int t = 0; t < 4; ++t) sc[t] = fzero4();
#pragma unroll
    for (int t = 0; t < 4; ++t) {
      int krow = ln * 4 + t;
      bf16x8 kb0 = lds_swzK(sK, krow, quad);
      bf16x8 kb1 = lds_swzK(sK, krow, 4 + quad);
      sc[t] = __builtin_amdgcn_mfma_f32_16x16x32_bf16(qf[0], kb0, sc[t], 0, 0, 0);
      sc[t] = __builtin_amdgcn_mfma_f32_16x16x32_bf16(qf[1], kb1, sc[t], 0, 0, 0);
    }

    // p = exp2(s); mask only on diagonal tile; truncation pack; b64 LDS writes
    if (kt == nkv - 1) {
#pragma unroll
      for (int r = 0; r < 4; ++r) {
        int row = qrow + quad * 4 + r;
        int colb = kv0 + ln * 4;
        float p0 = (colb + 0 <= row) ? __builtin_amdgcn_exp2f(sc[0][r]) : 0.0f;
        float p1 = (colb + 1 <= row) ? __builtin_amdgcn_exp2f(sc[1][r]) : 0.0f;
        float p2 = (colb + 2 <= row) ? __builtin_amdgcn_exp2f(sc[2][r]) : 0.0f;
        float p3 = (colb + 3 <= row) ? __builtin_amdgcn_exp2f(sc[3][r]) : 0.0f;
        *(uint2*)&pw[(quad * 4 + r) * 72 + ln * 4] = make_uint2(pk2t(p0, p1), pk2t(p2, p3));
      }
    } else {
#pragma unroll
      for (int r = 0; r < 4; ++r) {
        float p0 = __builtin_amdgcn_exp2f(sc[0][r]);
        float p1 = __builtin_amdgcn_exp2f(sc[1][r]);
        float p2 = __builtin_amdgcn_exp2f(sc[2][r]);
        float p3 = __builtin_amdgcn_exp2f(sc[3][r]);
        *(uint2*)&pw[(quad * 4 + r) * 72 + ln * 4] = make_uint2(pk2t(p0, p1), pk2t(p2, p3));
      }
    }

    // P fragments (A-layout), per-wave region -> no barrier needed
    bf16x8 pa0 = *(const bf16x8*)&pw[ln * 72 + quad * 8];
    bf16x8 pa1 = *(const bf16x8*)&pw[ln * 72 + 32 + quad * 8];

    // l += P @ ones
    l_acc = __builtin_amdgcn_mfma_f32_16x16x32_bf16(pa0, ones, l_acc, 0, 0, 0);
    l_acc = __builtin_amdgcn_mfma_f32_16x16x32_bf16(pa1, ones, l_acc, 0, 0, 0);

    // O += P @ V
#pragma unroll
    for (int t = 0; t < 4; ++t) {
      int vrow = t * 16 + ln;
      bf16x8 vb0 = lds_swzV(sV, vrow, quad);
      bf16x8 vb1 = lds_swzV(sV, vrow, 4 + quad);
      o_acc[t] = __builtin_amdgcn_mfma_f32_16x16x32_bf16(pa0, vb0, o_acc[t], 0, 0, 0);
      o_acc[t] = __builtin_amdgcn_mfma_f32_16x16x32_bf16(pa1, vb1, o_acc[t], 0, 0, 0);
    }
  }

  // epilogue: attn[s, h*64+hd] = O/l (bf16)
  float inv[4];
#pragma unroll
  for (int r = 0; r < 4; ++r) inv[r] = 1.0f / l_acc[r];
#pragma unroll
  for (int t = 0; t < 4; ++t)
#pragma unroll
    for (int r = 0; r < 4; ++r) {
      int row = qrow + quad * 4 + r;
      attn[(size_t)row * DIM + h * HD + t * 16 + ln] = f2b(o_acc[t][r] * inv[r]);
    }
}

extern "C" void kernel_launch(void* const* d_in, const int* in_sizes, int n_in,
                              void* d_out, int out_size, void* d_ws, size_t ws_size,
                              hipStream_t stream) {
  const float* x    = (const float*)d_in[0];
  const float* fc   = (const float*)d_in[2];
  const float* fs   = (const float*)d_in[3];
  const float* wqw  = (const float*)d_in[5];
  const float* wqb  = (const float*)d_in[6];
  const float* wkw  = (const float*)d_in[7];
  const float* wkb  = (const float*)d_in[8];
  const float* wvw  = (const float*)d_in[9];
  const float* wvb  = (const float*)d_in[10];
  const float* wow  = (const float*)d_in[11];
  const float* wobf = (const float*)d_in[12];
  float* out = (float*)d_out;

  char* ws = (char*)d_ws;
  const size_t MB = (size_t)1 << 20;
  unsigned short* xb    = (unsigned short*)(ws + 0);
  unsigned short* wqkvb = (unsigned short*)(ws + 8 * MB);
  unsigned short* wobb  = (unsigned short*)(ws + 16 * MB);
  float* biasq = (float*)(ws + 18 * MB);
  float* biaso = (float*)(ws + 18 * MB + 65536);
  unsigned short* qb_ = (unsigned short*)(ws + 19 * MB);
  unsigned short* kb_ = (unsigned short*)(ws + 27 * MB);
  unsigned short* vb_ = (unsigned short*)(ws + 35 * MB);
  unsigned short* vt  = (unsigned short*)(ws + 8 * MB);  // aliases wqkvb (dead after QKV GEMM)
  unsigned short* attn = (unsigned short*)(ws + 0);      // aliases xb (dead after QKV GEMM)

  cvt_all<<<8196, 256, 0, stream>>>(x, wqw, wkw, wvw, wow, wqb, wkb, wvb, wobf,
                                    xb, wqkvb, wobb, biasq, biaso);
  gemm_nt<<<dim3(32, 24), 256, 0, stream>>>(xb, wqkvb, biasq, nullptr, qb_, kb_, vb_,
                                            4096, 3072, 1024, 0);
  rope_kernel<<<4096, 256, 0, stream>>>(qb_, kb_, fc, fs);
  transpose_v<<<dim3(64, 16), 256, 0, stream>>>(vb_, vt);
  flash_kernel<<<dim3(64, 16), 256, 0, stream>>>(qb_, kb_, vt, attn);
  gemm_nt<<<dim3(32, 8), 256, 0, stream>>>(attn, wobb, biaso, out, nullptr, nullptr, nullptr,
                                           4096, 1024, 1024, 1);
}